// Round 17
// baseline (385.944 us; speedup 1.0000x reference)
//
#include <hip/hip_runtime.h>
#include <hip/hip_bf16.h>
#include <math.h>

#define MM 36

typedef _Float16 f16;
typedef __attribute__((ext_vector_type(8))) _Float16 f16x8;
typedef __attribute__((ext_vector_type(4))) _Float16 f16x4;
typedef __attribute__((ext_vector_type(4))) float f32x4;

enum { EPI_NONE = 0, EPI_SP = 1, EPI_TANH = 2, EPI_GATE = 3, EPI_DIAG = 4 };

// async global->LDS, 16B per lane. LDS dest must be wave-uniform base + lane*16.
__device__ __forceinline__ void gl_lds16(const f16* g, f16* l) {
    __builtin_amdgcn_global_load_lds(
        (const __attribute__((address_space(1))) void*)g,
        (__attribute__((address_space(3))) void*)l, 16, 0, 0);
}

// ============================================================================
// Counted-vmcnt GEMM template (R14-proven sync invariant: triple-buffer,
// prefetch distance 2, tile-end s_waitcnt vmcnt(L) THEN s_barrier).
// Configs:
//  fwd      : <EPI_SP,  64,128,256,4>  L=3, 36KB -> 4 blk/CU
//  fwd-out  : <EPI_TANH,128,128,256,2> L=4, 48KB -> 3 blk/CU
//  JVP      : <EPI_GATE,256,128,512,2> L=3, 72KB -> 2 blk/CU (occupancy fix)
//  diag     : <EPI_DIAG,128,128,256,2> L=4, z=field; atomicAdd into out
// ============================================================================
template <int EPI, int BM, int BN, int TPB, int WN>
__global__ __launch_bounds__(TPB, (163840 / (3 * (BM + BN) * 64)) * TPB / 256) void gemmCV(
    const f16* __restrict__ A, int lda, long aZ,
    const f16* __restrict__ W, int ldw, long wZ,
    const float* __restrict__ bias,
    f16* __restrict__ C, int ldc, long cZ,
    const f16* __restrict__ G,        // EPI_GATE: softplus buffer of this layer
    const f16* __restrict__ Vp,       // EPI_DIAG: V buffer
    float* __restrict__ outp,         // EPI_DIAG: output accumulator (f32)
    int b0,                           // EPI_DIAG: batch offset
    int K, int cshift)
{
    constexpr int WM = TPB / 64 / WN;
    constexpr int FM = BM / (WM * 16);
    constexpr int FN = BN / (WN * 16);
    constexpr int LA = BM * 4 / TPB;
    constexpr int LB = BN * 4 / TPB;
    constexpr int L  = LA + LB;

    __shared__ __align__(16) f16 smem[3 * (BM + BN) * 32];
    f16* bufA = smem;
    f16* bufB = smem + 3 * BM * 32;

    const int t = threadIdx.x;
    const int z = blockIdx.z;
    A += (size_t)z * aZ;
    W += (size_t)z * wZ;
    C += (size_t)z * cZ;

    const int nxy = gridDim.x * gridDim.y;
    const int orig = blockIdx.x + gridDim.x * blockIdx.y;
    const int q = nxy >> 3, r = nxy & 7;
    const int xcd = orig & 7, idx = orig >> 3;
    const int nid = (xcd < r ? xcd * (q + 1) : r * (q + 1) + (xcd - r) * q) + idx;
    const long rowTile = (long)(nid >> cshift) * BM;
    const long colTile = (long)(nid & ((1 << cshift) - 1)) * BN;

    const int wave = t >> 6;
    const int lane = t & 63;
    const int wr = (wave / WN) * (FM * 16);
    const int wc = (wave % WN) * (FN * 16);
    const int lr = lane & 15;
    const int lk = lane >> 4;
    const int rq = lk ^ (lr & 3);      // swizzled k-quad read slot
    const int srow = t >> 2;
    const int skq  = t & 3;

    f32x4 acc[FM][FN];
    const f32x4 zero = {0.f, 0.f, 0.f, 0.f};
#pragma unroll
    for (int m = 0; m < FM; ++m)
#pragma unroll
        for (int n = 0; n < FN; ++n) acc[m][n] = zero;

    const int nt = K >> 5;

    auto stage = [&](int buf, int tk) {
        const int k0 = tk << 5;
#pragma unroll
        for (int p = 0; p < LA; ++p) {
            const int row = srow + p * (TPB / 4);
            gl_lds16(A + (rowTile + row) * (long)lda + k0 + (skq ^ (row & 3)) * 8,
                     &bufA[buf * (BM * 32) + (p * TPB + t) * 8]);
        }
#pragma unroll
        for (int p = 0; p < LB; ++p) {
            const int row = srow + p * (TPB / 4);
            gl_lds16(W + (colTile + row) * (long)ldw + k0 + (skq ^ (row & 3)) * 8,
                     &bufB[buf * (BN * 32) + (p * TPB + t) * 8]);
        }
    };
    auto waitL = [&]() {
        if constexpr (L == 3) asm volatile("s_waitcnt vmcnt(3)" ::: "memory");
        else if constexpr (L == 4) asm volatile("s_waitcnt vmcnt(4)" ::: "memory");
        else asm volatile("s_waitcnt vmcnt(0)" ::: "memory");
    };

    // prologue: tiles 0,1; vmcnt(L) then barrier => tile 0 landed chip-wide
    stage(0, 0);
    stage(1, 1);
    waitL();
    __builtin_amdgcn_s_barrier();

    for (int tk = 0; tk < nt; ++tk) {
        const int cb = tk % 3;
        const f16* At = &bufA[cb * (BM * 32)];
        const f16* Bt = &bufB[cb * (BN * 32)];
        f16x8 a[FM], b[FN];
#pragma unroll
        for (int m = 0; m < FM; ++m)
            a[m] = *(const f16x8*)&At[(wr + m * 16 + lr) * 32 + rq * 8];
#pragma unroll
        for (int n = 0; n < FN; ++n)
            b[n] = *(const f16x8*)&Bt[(wc + n * 16 + lr) * 32 + rq * 8];
        if (tk + 2 < nt) stage((tk + 2) % 3, tk + 2);
        __builtin_amdgcn_s_setprio(1);
#pragma unroll
        for (int m = 0; m < FM; ++m)
#pragma unroll
            for (int n = 0; n < FN; ++n)
                acc[m][n] = __builtin_amdgcn_mfma_f32_16x16x32_f16(a[m], b[n], acc[m][n], 0, 0, 0);
        __builtin_amdgcn_s_setprio(0);
        // tile-end sync (R14 invariant): vmcnt THEN barrier
        if (tk + 1 < nt) {
            if (tk + 2 < nt) waitL();
            else asm volatile("s_waitcnt vmcnt(0)" ::: "memory");
            __builtin_amdgcn_s_barrier();
        }
    }

    // ---- epilogue: EPI -> LDS (xor-swizzled) -> coalesced f16x8 accesses ----
    __syncthreads();
#pragma unroll
    for (int m = 0; m < FM; ++m) {
#pragma unroll
        for (int n = 0; n < FN; ++n) {
            const int lcol = wc + n * 16 + lr;
            const float bb = bias ? bias[colTile + lcol] : 0.f;
#pragma unroll
            for (int j = 0; j < 4; ++j) {
                const int lrow = wr + m * 16 + lk * 4 + j;
                const int lidx = lrow * BN + (lcol ^ (lk * 16));
                const float x = acc[m][n][j] + bb;
                if constexpr (EPI == EPI_SP) {
                    const float e = __expf(-fabsf(x));
                    smem[lidx] = (f16)(fmaxf(x, 0.f) + __logf(1.f + e));
                } else if constexpr (EPI == EPI_TANH) {
                    const float e2 = __expf(2.f * x);
                    smem[lidx] = (f16)(1.f - 2.f * __builtin_amdgcn_rcpf(e2 + 1.f));
                } else if constexpr (EPI == EPI_GATE) {
                    const long row = rowTile + lrow;
                    const float s = (float)G[(row >> 3) * ldc + colTile + lcol];
                    smem[lidx] = (f16)(x * (1.f - __expf(-s)));
                } else {
                    smem[lidx] = (f16)x;   // NONE / DIAG
                }
            }
        }
    }
    __syncthreads();
#pragma unroll
    for (int p = 0; p < BM * BN / (8 * TPB); ++p) {
        const int c = p * TPB + t;
        const int rl = c / (BN / 8);
        const int c16 = (c % (BN / 8)) * 8;
        const f16x8 v = *(const f16x8*)&smem[rl * BN + (c16 ^ (((rl >> 2) & 3) * 16))];
        if constexpr (EPI == EPI_DIAG) {
            // out[b0+row, col] += (1 - V^2) * Oi ; V[row, z*256+col]
            const long row = rowTile + rl;
            const f16x8 v8 = *(const f16x8*)&Vp[row * 2048 + z * 256 + colTile + c16];
            float* op = &outp[(size_t)(b0 + row) * 256 + colTile + c16];
#pragma unroll
            for (int e = 0; e < 8; ++e) {
                const float vv = (float)v8[e];
                atomicAdd(&op[e], (1.f - vv * vv) * (float)v[e]);
            }
        } else {
            *(f16x8*)&C[(rowTile + rl) * ldc + colTile + c16] = v;
        }
    }
}

// T[b,i,n] = sum_{k<i} sig2[(k,i)] V[b,k,n] - sum_{k>i} sig2[(i,k)] V[b,k,n]
// ALSO writes the level-1 base term: out[b,n] = sum_i sig[b,i] * V[b,i,n]
// (the diag kernel then atomicAdds the (1-V^2)*Oi terms on top).
__global__ __launch_bounds__(256) void ktilde16(
    const f16* __restrict__ V, const float* __restrict__ sig,
    f16* __restrict__ T, float* __restrict__ out, int b0)
{
    const int bl = blockIdx.x * 4 + (threadIdx.x >> 6);
    const int n0 = (threadIdx.x & 63) * 4;
    const f16* vb = V + (size_t)bl * 2048 + n0;
    float v[8][4];
#pragma unroll
    for (int k = 0; k < 8; ++k) {
        const f16x4 x = *(const f16x4*)&vb[k * 256];
#pragma unroll
        for (int j = 0; j < 4; ++j) v[k][j] = (float)x[j];
    }
    const float* sg = sig + (size_t)(b0 + bl) * MM;
    float s1v[8], s2[28];
#pragma unroll
    for (int k = 0; k < 8; ++k) s1v[k] = sg[k];
#pragma unroll
    for (int p = 0; p < 28; ++p) s2[p] = sg[8 + p];

    // base term -> out (overwritten fresh every call; diag adds on top)
    {
        float b0v = 0.f, b1v = 0.f, b2v = 0.f, b3v = 0.f;
#pragma unroll
        for (int k = 0; k < 8; ++k) {
            b0v = fmaf(s1v[k], v[k][0], b0v); b1v = fmaf(s1v[k], v[k][1], b1v);
            b2v = fmaf(s1v[k], v[k][2], b2v); b3v = fmaf(s1v[k], v[k][3], b3v);
        }
        float4 ov; ov.x = b0v; ov.y = b1v; ov.z = b2v; ov.w = b3v;
        *(float4*)&out[(size_t)(b0 + bl) * 256 + n0] = ov;
    }

    f16* tb = T + (size_t)bl * 2048 + n0;
#pragma unroll
    for (int i = 0; i < 8; ++i) {
        float a0 = 0.f, a1 = 0.f, a2 = 0.f, a3 = 0.f;
#pragma unroll
        for (int k = 0; k < 8; ++k) {
            if (k == i) continue;
            const int a = (k < i) ? k : i;
            const int b = (k < i) ? i : k;
            const int p = a * (15 - a) / 2 + (b - a - 1);
            const float c = (k < i) ? s2[p] : -s2[p];
            a0 = fmaf(c, v[k][0], a0); a1 = fmaf(c, v[k][1], a1);
            a2 = fmaf(c, v[k][2], a2); a3 = fmaf(c, v[k][3], a3);
        }
        f16x4 o;
        o[0] = (f16)a0; o[1] = (f16)a1; o[2] = (f16)a2; o[3] = (f16)a3;
        *(f16x4*)&tb[i * 256] = o;
    }
}

// one-shot f32->f16 of all four weight matrices (float4 granularity)
__global__ __launch_bounds__(256) void cvtW(
    const float* __restrict__ W1, const float* __restrict__ W2,
    const float* __restrict__ W3, const float* __restrict__ Wo,
    f16* __restrict__ o1, f16* __restrict__ o2,
    f16* __restrict__ o3, f16* __restrict__ oo)
{
    long i = (long)blockIdx.x * 256 + threadIdx.x;
    const float* src; f16* dst; long base;
    if (i < 32768)       { src = W1; dst = o1; base = 0; }
    else if (i < 98304)  { src = W2; dst = o2; base = 32768; }
    else if (i < 163840) { src = W3; dst = o3; base = 98304; }
    else                 { src = Wo; dst = oo; base = 163840; }
    i -= base;
    const float4 v = ((const float4*)src)[i];
    f16x4 o;
    o[0] = (f16)v.x; o[1] = (f16)v.y; o[2] = (f16)v.z; o[3] = (f16)v.w;
    ((f16x4*)dst)[i] = o;
}

__global__ __launch_bounds__(256) void cvt16(
    const float* __restrict__ x, f16* __restrict__ y, int n)
{
    const int i = (blockIdx.x * 256 + threadIdx.x) * 4;
    if (i < n) {
        const float4 v = *(const float4*)&x[i];
        f16x4 o;
        o[0] = (f16)v.x; o[1] = (f16)v.y; o[2] = (f16)v.z; o[3] = (f16)v.w;
        *(f16x4*)&y[i] = o;
    }
}

extern "C" void kernel_launch(void* const* d_in, const int* in_sizes, int n_in,
                              void* d_out, int out_size, void* d_ws, size_t ws_size,
                              hipStream_t stream) {
    const float* h   = (const float*)d_in[0];
    const float* sig = (const float*)d_in[1];
    const float* W1  = (const float*)d_in[2];
    const float* b1  = (const float*)d_in[3];
    const float* W2  = (const float*)d_in[4];
    const float* b2  = (const float*)d_in[5];
    const float* W3  = (const float*)d_in[6];
    const float* b3  = (const float*)d_in[7];
    const float* Wo  = (const float*)d_in[8];
    const float* bo  = (const float*)d_in[9];
    float* out = (float*)d_out;

    char* p = (char*)d_ws;
    f16* W1h = (f16*)p; p += (size_t)512 * 256 * 2;
    f16* W2h = (f16*)p; p += (size_t)512 * 512 * 2;
    f16* W3h = (f16*)p; p += (size_t)512 * 512 * 2;
    f16* Woh = (f16*)p; p += (size_t)2048 * 512 * 2;
    const size_t fixed = (size_t)(p - (char*)d_ws);

    int C = 4096;
    while (C > 128 && fixed + (size_t)C * 28160 > ws_size) C >>= 1;

    f16* h16 = (f16*)p; p += (size_t)C * 256 * 2;
    f16* s1 = (f16*)p;  p += (size_t)C * 512 * 2;
    f16* s2 = (f16*)p;  p += (size_t)C * 512 * 2;
    f16* s3 = (f16*)p;  p += (size_t)C * 512 * 2;
    f16* V  = (f16*)p;  p += (size_t)C * 2048 * 2;
    f16* T  = (f16*)p;  p += (size_t)C * 2048 * 2;
    f16* Ua = (f16*)p;  p += (size_t)C * 4096 * 2;
    f16* Ub = (f16*)p;

    const dim3 blk(256);
    const dim3 blk5(512);
    cvtW<<<dim3(1664), blk, 0, stream>>>(W1, W2, W3, Wo, W1h, W2h, W3h, Woh);

    for (int b0 = 0; b0 < 4096; b0 += C) {
        cvt16<<<dim3(C * 256 / 1024), blk, 0, stream>>>(h + (size_t)b0 * 256, h16, C * 256);
        // Forward MLP (counted-vmcnt template)
        gemmCV<EPI_SP, 64, 128, 256, 4><<<dim3(4, C / 64), blk, 0, stream>>>(
            h16, 256, 0, W1h, 256, 0, b1, s1, 512, 0, nullptr, nullptr, nullptr, 0, 256, 2);
        gemmCV<EPI_SP, 64, 128, 256, 4><<<dim3(4, C / 64), blk, 0, stream>>>(
            s1, 512, 0, W2h, 512, 0, b2, s2, 512, 0, nullptr, nullptr, nullptr, 0, 512, 2);
        gemmCV<EPI_SP, 64, 128, 256, 4><<<dim3(4, C / 64), blk, 0, stream>>>(
            s2, 512, 0, W3h, 512, 0, b3, s3, 512, 0, nullptr, nullptr, nullptr, 0, 512, 2);
        gemmCV<EPI_TANH, 128, 128, 256, 2><<<dim3(16, C / 128), blk, 0, stream>>>(
            s3, 512, 0, Woh, 512, 0, bo, V, 2048, 0, nullptr, nullptr, nullptr, 0, 512, 4);
        // Signature-mixed tangents + base term into out
        ktilde16<<<dim3(C / 4), blk, 0, stream>>>(V, sig, T, out, b0);
        // JVP chain: 256x128 counted-vmcnt @ 2 blocks/CU (occupancy fix)
        gemmCV<EPI_GATE, 256, 128, 512, 2><<<dim3(4, C * 8 / 256), blk5, 0, stream>>>(
            T, 256, 0, W1h, 256, 0, nullptr, Ua, 512, 0, s1, nullptr, nullptr, 0, 256, 2);
        gemmCV<EPI_GATE, 256, 128, 512, 2><<<dim3(4, C * 8 / 256), blk5, 0, stream>>>(
            Ua, 512, 0, W2h, 512, 0, nullptr, Ub, 512, 0, s2, nullptr, nullptr, 0, 512, 2);
        gemmCV<EPI_GATE, 256, 128, 512, 2><<<dim3(4, C * 8 / 256), blk5, 0, stream>>>(
            Ub, 512, 0, W3h, 512, 0, nullptr, Ua, 512, 0, s3, nullptr, nullptr, 0, 512, 2);
        // Per-field diagonal last-layer JVP fused with the final contraction:
        // atomicAdd (1-V^2)*Oi into out (base term written by ktilde16).
        gemmCV<EPI_DIAG, 128, 128, 256, 2><<<dim3(2, C / 128, 8), blk, 0, stream>>>(
            Ua, 4096, 512, Woh, 512, (long)256 * 512, nullptr, nullptr, 256, 0,
            nullptr, V, out, b0, 512, 1);
    }
}

// Round 19
// 169.843 us; speedup vs baseline: 2.2724x; 2.2724x over previous
//
#include <hip/hip_runtime.h>
#include <hip/hip_bf16.h>
#include <math.h>

#define MM 36

typedef _Float16 f16;
typedef __attribute__((ext_vector_type(8))) _Float16 f16x8;
typedef __attribute__((ext_vector_type(4))) _Float16 f16x4;
typedef __attribute__((ext_vector_type(4))) float f32x4;

enum { EPI_NONE = 0, EPI_SP = 1, EPI_TANH = 2, EPI_GATE = 3 };

// async global->LDS, 16B per lane. LDS dest must be wave-uniform base + lane*16.
__device__ __forceinline__ void gl_lds16(const f16* g, f16* l) {
    __builtin_amdgcn_global_load_lds(
        (const __attribute__((address_space(1))) void*)g,
        (__attribute__((address_space(3))) void*)l, 16, 0, 0);
}

// ============================================================================
// Counted-vmcnt GEMM template (R14-proven sync invariant: triple-buffer,
// prefetch distance 2, tile-end s_waitcnt vmcnt(L) THEN s_barrier).
// Configs (all individually validated R14/R16/R17):
//  fwd      : <EPI_SP,  64,128,256,4>  L=3, 36KB -> 4 blk/CU
//  fwd-out  : <EPI_TANH,128,128,256,2> L=4, 48KB -> 3 blk/CU
//  JVP      : <EPI_GATE,256,128,512,2> L=3, 72KB -> 2 blk/CU (R17-validated)
//  diag     : <EPI_NONE,128,128,256,2> L=4, z=field -> Oi f16 (R16-validated)
// ============================================================================
template <int EPI, int BM, int BN, int TPB, int WN>
__global__ __launch_bounds__(TPB, (163840 / (3 * (BM + BN) * 64)) * TPB / 256) void gemmCV(
    const f16* __restrict__ A, int lda, long aZ,
    const f16* __restrict__ W, int ldw, long wZ,
    const float* __restrict__ bias,
    f16* __restrict__ C, int ldc, long cZ,
    const f16* __restrict__ G,        // EPI_GATE: softplus buffer of this layer
    int K, int cshift)
{
    constexpr int WM = TPB / 64 / WN;
    constexpr int FM = BM / (WM * 16);
    constexpr int FN = BN / (WN * 16);
    constexpr int LA = BM * 4 / TPB;
    constexpr int LB = BN * 4 / TPB;
    constexpr int L  = LA + LB;

    __shared__ __align__(16) f16 smem[3 * (BM + BN) * 32];
    f16* bufA = smem;
    f16* bufB = smem + 3 * BM * 32;

    const int t = threadIdx.x;
    const int z = blockIdx.z;
    A += (size_t)z * aZ;
    W += (size_t)z * wZ;
    C += (size_t)z * cZ;

    const int nxy = gridDim.x * gridDim.y;
    const int orig = blockIdx.x + gridDim.x * blockIdx.y;
    const int q = nxy >> 3, r = nxy & 7;
    const int xcd = orig & 7, idx = orig >> 3;
    const int nid = (xcd < r ? xcd * (q + 1) : r * (q + 1) + (xcd - r) * q) + idx;
    const long rowTile = (long)(nid >> cshift) * BM;
    const long colTile = (long)(nid & ((1 << cshift) - 1)) * BN;

    const int wave = t >> 6;
    const int lane = t & 63;
    const int wr = (wave / WN) * (FM * 16);
    const int wc = (wave % WN) * (FN * 16);
    const int lr = lane & 15;
    const int lk = lane >> 4;
    const int rq = lk ^ (lr & 3);      // swizzled k-quad read slot
    const int srow = t >> 2;
    const int skq  = t & 3;

    f32x4 acc[FM][FN];
    const f32x4 zero = {0.f, 0.f, 0.f, 0.f};
#pragma unroll
    for (int m = 0; m < FM; ++m)
#pragma unroll
        for (int n = 0; n < FN; ++n) acc[m][n] = zero;

    const int nt = K >> 5;

    auto stage = [&](int buf, int tk) {
        const int k0 = tk << 5;
#pragma unroll
        for (int p = 0; p < LA; ++p) {
            const int row = srow + p * (TPB / 4);
            gl_lds16(A + (rowTile + row) * (long)lda + k0 + (skq ^ (row & 3)) * 8,
                     &bufA[buf * (BM * 32) + (p * TPB + t) * 8]);
        }
#pragma unroll
        for (int p = 0; p < LB; ++p) {
            const int row = srow + p * (TPB / 4);
            gl_lds16(W + (colTile + row) * (long)ldw + k0 + (skq ^ (row & 3)) * 8,
                     &bufB[buf * (BN * 32) + (p * TPB + t) * 8]);
        }
    };
    auto waitL = [&]() {
        if constexpr (L == 3) asm volatile("s_waitcnt vmcnt(3)" ::: "memory");
        else if constexpr (L == 4) asm volatile("s_waitcnt vmcnt(4)" ::: "memory");
        else asm volatile("s_waitcnt vmcnt(0)" ::: "memory");
    };

    // prologue: tiles 0,1; vmcnt(L) then barrier => tile 0 landed chip-wide
    stage(0, 0);
    stage(1, 1);
    waitL();
    __builtin_amdgcn_s_barrier();

    for (int tk = 0; tk < nt; ++tk) {
        const int cb = tk % 3;
        const f16* At = &bufA[cb * (BM * 32)];
        const f16* Bt = &bufB[cb * (BN * 32)];
        f16x8 a[FM], b[FN];
#pragma unroll
        for (int m = 0; m < FM; ++m)
            a[m] = *(const f16x8*)&At[(wr + m * 16 + lr) * 32 + rq * 8];
#pragma unroll
        for (int n = 0; n < FN; ++n)
            b[n] = *(const f16x8*)&Bt[(wc + n * 16 + lr) * 32 + rq * 8];
        if (tk + 2 < nt) stage((tk + 2) % 3, tk + 2);
        __builtin_amdgcn_s_setprio(1);
#pragma unroll
        for (int m = 0; m < FM; ++m)
#pragma unroll
            for (int n = 0; n < FN; ++n)
                acc[m][n] = __builtin_amdgcn_mfma_f32_16x16x32_f16(a[m], b[n], acc[m][n], 0, 0, 0);
        __builtin_amdgcn_s_setprio(0);
        // tile-end sync (R14 invariant): vmcnt THEN barrier
        if (tk + 1 < nt) {
            if (tk + 2 < nt) waitL();
            else asm volatile("s_waitcnt vmcnt(0)" ::: "memory");
            __builtin_amdgcn_s_barrier();
        }
    }

    // ---- epilogue: EPI -> LDS (xor-swizzled) -> coalesced f16x8 stores ----
    __syncthreads();
#pragma unroll
    for (int m = 0; m < FM; ++m) {
#pragma unroll
        for (int n = 0; n < FN; ++n) {
            const int lcol = wc + n * 16 + lr;
            const float bb = bias ? bias[colTile + lcol] : 0.f;
#pragma unroll
            for (int j = 0; j < 4; ++j) {
                const int lrow = wr + m * 16 + lk * 4 + j;
                const int lidx = lrow * BN + (lcol ^ (lk * 16));
                const float x = acc[m][n][j] + bb;
                if constexpr (EPI == EPI_SP) {
                    const float e = __expf(-fabsf(x));
                    smem[lidx] = (f16)(fmaxf(x, 0.f) + __logf(1.f + e));
                } else if constexpr (EPI == EPI_TANH) {
                    const float e2 = __expf(2.f * x);
                    smem[lidx] = (f16)(1.f - 2.f * __builtin_amdgcn_rcpf(e2 + 1.f));
                } else if constexpr (EPI == EPI_GATE) {
                    const long row = rowTile + lrow;
                    const float s = (float)G[(row >> 3) * ldc + colTile + lcol];
                    smem[lidx] = (f16)(x * (1.f - __expf(-s)));
                } else {
                    smem[lidx] = (f16)x;
                }
            }
        }
    }
    __syncthreads();
#pragma unroll
    for (int p = 0; p < BM * BN / (8 * TPB); ++p) {
        const int c = p * TPB + t;
        const int rl = c / (BN / 8);
        const int c16 = (c % (BN / 8)) * 8;
        const f16x8 v = *(const f16x8*)&smem[rl * BN + (c16 ^ (((rl >> 2) & 3) * 16))];
        *(f16x8*)&C[(rowTile + rl) * ldc + colTile + c16] = v;
    }
}

// T[b,i,n] = sum_{k<i} sig2[(k,i)] V[b,k,n] - sum_{k>i} sig2[(i,k)] V[b,k,n]
__global__ __launch_bounds__(256) void ktilde16(
    const f16* __restrict__ V, const float* __restrict__ sig,
    f16* __restrict__ T, int b0)
{
    const int bl = blockIdx.x * 4 + (threadIdx.x >> 6);
    const int n0 = (threadIdx.x & 63) * 4;
    const f16* vb = V + (size_t)bl * 2048 + n0;
    float v[8][4];
#pragma unroll
    for (int k = 0; k < 8; ++k) {
        const f16x4 x = *(const f16x4*)&vb[k * 256];
#pragma unroll
        for (int j = 0; j < 4; ++j) v[k][j] = (float)x[j];
    }
    const float* sg = sig + (size_t)(b0 + bl) * MM + 8;
    float s2[28];
#pragma unroll
    for (int p = 0; p < 28; ++p) s2[p] = sg[p];

    f16* tb = T + (size_t)bl * 2048 + n0;
#pragma unroll
    for (int i = 0; i < 8; ++i) {
        float a0 = 0.f, a1 = 0.f, a2 = 0.f, a3 = 0.f;
#pragma unroll
        for (int k = 0; k < 8; ++k) {
            if (k == i) continue;
            const int a = (k < i) ? k : i;
            const int b = (k < i) ? i : k;
            const int p = a * (15 - a) / 2 + (b - a - 1);
            const float c = (k < i) ? s2[p] : -s2[p];
            a0 = fmaf(c, v[k][0], a0); a1 = fmaf(c, v[k][1], a1);
            a2 = fmaf(c, v[k][2], a2); a3 = fmaf(c, v[k][3], a3);
        }
        f16x4 o;
        o[0] = (f16)a0; o[1] = (f16)a1; o[2] = (f16)a2; o[3] = (f16)a3;
        *(f16x4*)&tb[i * 256] = o;
    }
}

// out[b,n] = sum_i sig[b,i]*V[b,i,n] + (1 - V^2) * Oi[i][b][n]   (Oi is f16)
__global__ __launch_bounds__(256) void finish16(
    const f16* __restrict__ V, const f16* __restrict__ Oi,
    const float* __restrict__ sig, float* __restrict__ out, int b0, int C)
{
    const int bl = blockIdx.x * 4 + (threadIdx.x >> 6);
    const int n0 = (threadIdx.x & 63) * 4;
    const float* sg = sig + (size_t)(b0 + bl) * MM;
    float a0 = 0.f, a1 = 0.f, a2 = 0.f, a3 = 0.f;
#pragma unroll
    for (int i = 0; i < 8; ++i) {
        const f16x4 vv = *(const f16x4*)&V[(size_t)bl * 2048 + i * 256 + n0];
        const f16x4 oo = *(const f16x4*)&Oi[((size_t)i * C + bl) * 256 + n0];
        const float s = sg[i];
        const float v0 = (float)vv[0], v1 = (float)vv[1];
        const float v2 = (float)vv[2], v3 = (float)vv[3];
        a0 = fmaf(s, v0, a0); a0 = fmaf(1.f - v0 * v0, (float)oo[0], a0);
        a1 = fmaf(s, v1, a1); a1 = fmaf(1.f - v1 * v1, (float)oo[1], a1);
        a2 = fmaf(s, v2, a2); a2 = fmaf(1.f - v2 * v2, (float)oo[2], a2);
        a3 = fmaf(s, v3, a3); a3 = fmaf(1.f - v3 * v3, (float)oo[3], a3);
    }
    float4 ov; ov.x = a0; ov.y = a1; ov.z = a2; ov.w = a3;
    *(float4*)&out[(size_t)(b0 + bl) * 256 + n0] = ov;
}

// one-shot f32->f16 of all four weight matrices (float4 granularity)
__global__ __launch_bounds__(256) void cvtW(
    const float* __restrict__ W1, const float* __restrict__ W2,
    const float* __restrict__ W3, const float* __restrict__ Wo,
    f16* __restrict__ o1, f16* __restrict__ o2,
    f16* __restrict__ o3, f16* __restrict__ oo)
{
    long i = (long)blockIdx.x * 256 + threadIdx.x;
    const float* src; f16* dst; long base;
    if (i < 32768)       { src = W1; dst = o1; base = 0; }
    else if (i < 98304)  { src = W2; dst = o2; base = 32768; }
    else if (i < 163840) { src = W3; dst = o3; base = 98304; }
    else                 { src = Wo; dst = oo; base = 163840; }
    i -= base;
    const float4 v = ((const float4*)src)[i];
    f16x4 o;
    o[0] = (f16)v.x; o[1] = (f16)v.y; o[2] = (f16)v.z; o[3] = (f16)v.w;
    ((f16x4*)dst)[i] = o;
}

__global__ __launch_bounds__(256) void cvt16(
    const float* __restrict__ x, f16* __restrict__ y, int n)
{
    const int i = (blockIdx.x * 256 + threadIdx.x) * 4;
    if (i < n) {
        const float4 v = *(const float4*)&x[i];
        f16x4 o;
        o[0] = (f16)v.x; o[1] = (f16)v.y; o[2] = (f16)v.z; o[3] = (f16)v.w;
        *(f16x4*)&y[i] = o;
    }
}

extern "C" void kernel_launch(void* const* d_in, const int* in_sizes, int n_in,
                              void* d_out, int out_size, void* d_ws, size_t ws_size,
                              hipStream_t stream) {
    const float* h   = (const float*)d_in[0];
    const float* sig = (const float*)d_in[1];
    const float* W1  = (const float*)d_in[2];
    const float* b1  = (const float*)d_in[3];
    const float* W2  = (const float*)d_in[4];
    const float* b2  = (const float*)d_in[5];
    const float* W3  = (const float*)d_in[6];
    const float* b3  = (const float*)d_in[7];
    const float* Wo  = (const float*)d_in[8];
    const float* bo  = (const float*)d_in[9];
    float* out = (float*)d_out;

    char* p = (char*)d_ws;
    f16* W1h = (f16*)p; p += (size_t)512 * 256 * 2;
    f16* W2h = (f16*)p; p += (size_t)512 * 512 * 2;
    f16* W3h = (f16*)p; p += (size_t)512 * 512 * 2;
    f16* Woh = (f16*)p; p += (size_t)2048 * 512 * 2;
    const size_t fixed = (size_t)(p - (char*)d_ws);

    int C = 4096;
    while (C > 128 && fixed + (size_t)C * 28160 > ws_size) C >>= 1;

    f16* h16 = (f16*)p; p += (size_t)C * 256 * 2;
    f16* s1 = (f16*)p;  p += (size_t)C * 512 * 2;
    f16* s2 = (f16*)p;  p += (size_t)C * 512 * 2;
    f16* s3 = (f16*)p;  p += (size_t)C * 512 * 2;
    f16* V  = (f16*)p;  p += (size_t)C * 2048 * 2;
    f16* T  = (f16*)p;  p += (size_t)C * 2048 * 2;
    f16* Ua = (f16*)p;  p += (size_t)C * 4096 * 2;
    f16* Ub = (f16*)p;
    f16* Oi = Ub;                         // 8 x C x 256 f16 (Ub dead before diag)

    const dim3 blk(256);
    const dim3 blk5(512);
    cvtW<<<dim3(1664), blk, 0, stream>>>(W1, W2, W3, Wo, W1h, W2h, W3h, Woh);

    for (int b0 = 0; b0 < 4096; b0 += C) {
        cvt16<<<dim3(C * 256 / 1024), blk, 0, stream>>>(h + (size_t)b0 * 256, h16, C * 256);
        // Forward MLP (counted-vmcnt template)
        gemmCV<EPI_SP, 64, 128, 256, 4><<<dim3(4, C / 64), blk, 0, stream>>>(
            h16, 256, 0, W1h, 256, 0, b1, s1, 512, 0, nullptr, 256, 2);
        gemmCV<EPI_SP, 64, 128, 256, 4><<<dim3(4, C / 64), blk, 0, stream>>>(
            s1, 512, 0, W2h, 512, 0, b2, s2, 512, 0, nullptr, 512, 2);
        gemmCV<EPI_SP, 64, 128, 256, 4><<<dim3(4, C / 64), blk, 0, stream>>>(
            s2, 512, 0, W3h, 512, 0, b3, s3, 512, 0, nullptr, 512, 2);
        gemmCV<EPI_TANH, 128, 128, 256, 2><<<dim3(16, C / 128), blk, 0, stream>>>(
            s3, 512, 0, Woh, 512, 0, bo, V, 2048, 0, nullptr, 512, 4);
        // Signature-mixed tangents
        ktilde16<<<dim3(C / 4), blk, 0, stream>>>(V, sig, T, b0);
        // JVP chain: 256x128 counted-vmcnt @ 2 blocks/CU (R17-validated, ~5.5us win)
        gemmCV<EPI_GATE, 256, 128, 512, 2><<<dim3(4, C * 8 / 256), blk5, 0, stream>>>(
            T, 256, 0, W1h, 256, 0, nullptr, Ua, 512, 0, s1, 256, 2);
        gemmCV<EPI_GATE, 256, 128, 512, 2><<<dim3(4, C * 8 / 256), blk5, 0, stream>>>(
            Ua, 512, 0, W2h, 512, 0, nullptr, Ub, 512, 0, s2, 512, 2);
        gemmCV<EPI_GATE, 256, 128, 512, 2><<<dim3(4, C * 8 / 256), blk5, 0, stream>>>(
            Ub, 512, 0, W3h, 512, 0, nullptr, Ua, 512, 0, s3, 512, 2);
        // Per-field diagonal last-layer JVP (z = field), Oi stored f16 (R16 form)
        gemmCV<EPI_NONE, 128, 128, 256, 2><<<dim3(2, C / 128, 8), blk, 0, stream>>>(
            Ua, 4096, 512, Woh, 512, (long)256 * 512, nullptr, Oi, 256, (long)C * 256,
            nullptr, 512, 1);
        // Final contraction
        finish16<<<dim3(C / 4), blk, 0, stream>>>(V, Oi, sig, out, b0, C);
    }
}

// Round 20
// 160.321 us; speedup vs baseline: 2.4073x; 1.0594x over previous
//
#include <hip/hip_runtime.h>
#include <hip/hip_bf16.h>
#include <math.h>

#define MM 36

typedef _Float16 f16;
typedef __attribute__((ext_vector_type(8))) _Float16 f16x8;
typedef __attribute__((ext_vector_type(4))) _Float16 f16x4;
typedef __attribute__((ext_vector_type(4))) float f32x4;

enum { EPI_NONE = 0, EPI_SP = 1, EPI_TANH = 2, EPI_GATE = 3 };

// async global->LDS, 16B per lane. LDS dest must be wave-uniform base + lane*16.
__device__ __forceinline__ void gl_lds16(const f16* g, f16* l) {
    __builtin_amdgcn_global_load_lds(
        (const __attribute__((address_space(1))) void*)g,
        (__attribute__((address_space(3))) void*)l, 16, 0, 0);
}

// ============================================================================
// JVP counted-vmcnt GEMM (R14-proven invariant, deepened to distance-3):
// C = gate * A W^T, 256x256 tile, BK=32, 512 thr, QUAD-buffer (128KB LDS),
// prefetch distance 3 (~960cy in-flight >= ~900cy HBM latency; distance 2's
// ~640cy was short -> tile-end stall). Sync: at tile-t end, stages cover
// <= t+3, so awaiting tile t+1 allows 8 outstanding: vmcnt(8)/4/0 ladder,
// THEN s_barrier (vmcnt-before-barrier => chip-wide visibility, R14 fix).
// WAR: buf[(t+3)%4] last read tile t-1, behind its barrier. 1 blk/CU (as
// before - occupancy unchanged, so nothing traded away).
// ============================================================================
__global__ __launch_bounds__(512, 1) void gemm8p(
    const f16* __restrict__ A, int lda,
    const f16* __restrict__ W, int ldw,
    f16* __restrict__ C, int ldc,
    const f16* __restrict__ G,
    int K)
{
    __shared__ __align__(16) f16 smem[65536];   // 4 x (8192 A + 8192 B) = 128 KB
    f16* bufA = smem;
    f16* bufB = smem + 32768;

    const int t = threadIdx.x;
    const int nxy = gridDim.x * gridDim.y;      // divisible by 8
    const int orig = blockIdx.x + gridDim.x * blockIdx.y;
    const int q = nxy >> 3, r = nxy & 7;
    const int xcd = orig & 7, idx = orig >> 3;
    const int nid = (xcd < r ? xcd * (q + 1) : r * (q + 1) + (xcd - r) * q) + idx;
    const long rowTile = (long)(nid >> 1) * 256;
    const long colTile = (long)(nid & 1) * 256;

    const int wave = t >> 6;
    const int lane = t & 63;
    const int wm = wave >> 2;           // 0..1 (row half)
    const int wn = wave & 3;            // 0..3 (col quarter)
    const int lr = lane & 15;
    const int lk = lane >> 4;           // k-group
    const int rq = lk ^ (lr & 3);       // swizzled k-quad for frag reads

    const int srow = t >> 2;            // staging row (pass p adds 128)
    const int skq  = t & 3;             // staging k-quad (pre-swizzled source)

    f32x4 acc[8][4];
    const f32x4 zero = {0.f, 0.f, 0.f, 0.f};
#pragma unroll
    for (int m = 0; m < 8; ++m)
#pragma unroll
        for (int n = 0; n < 4; ++n) acc[m][n] = zero;

    const int nt = K >> 5;

    auto stageA = [&](int buf, int tk) {
        const int k0 = tk << 5;
#pragma unroll
        for (int p = 0; p < 2; ++p) {
            const int row = srow + p * 128;
            gl_lds16(A + (rowTile + row) * (long)lda + k0 + (skq ^ (row & 3)) * 8,
                     &bufA[buf * 8192 + (p * 512 + t) * 8]);
        }
    };
    auto stageB = [&](int buf, int tk) {
        const int k0 = tk << 5;
#pragma unroll
        for (int p = 0; p < 2; ++p) {
            const int row = srow + p * 128;
            gl_lds16(W + (colTile + row) * (long)ldw + k0 + (skq ^ (row & 3)) * 8,
                     &bufB[buf * 8192 + (p * 512 + t) * 8]);
        }
    };

    // prologue: stage K-tiles 0,1,2; await tile 0 (8 newer loads allowed)
    stageA(0, 0); stageB(0, 0);
    stageA(1, 1); stageB(1, 1);
    stageA(2, 2); stageB(2, 2);
    asm volatile("s_waitcnt vmcnt(8)" ::: "memory");   // own tile-0 loads landed
    __builtin_amdgcn_s_barrier();                       // => ALL waves' landed

    for (int tk = 0; tk < nt; ++tk) {
        const int cb = tk & 3;
        const int sb = (tk + 3) & 3;
        const f16* At = &bufA[cb * 8192];
        const f16* Bt = &bufB[cb * 8192];
        f16x8 a[4], b[4];
        // ---- phase 0: rows 0-63 of wave half ----
#pragma unroll
        for (int m = 0; m < 4; ++m)
            a[m] = *(const f16x8*)&At[(wm * 128 + m * 16 + lr) * 32 + rq * 8];
#pragma unroll
        for (int n = 0; n < 4; ++n)
            b[n] = *(const f16x8*)&Bt[(wn * 64 + n * 16 + lr) * 32 + rq * 8];
        if (tk + 3 < nt) stageA(sb, tk + 3);
        __builtin_amdgcn_s_setprio(1);
#pragma unroll
        for (int m = 0; m < 4; ++m)
#pragma unroll
            for (int n = 0; n < 4; ++n)
                acc[m][n] = __builtin_amdgcn_mfma_f32_16x16x32_f16(a[m], b[n], acc[m][n], 0, 0, 0);
        __builtin_amdgcn_s_setprio(0);
        // ---- phase 1: rows 64-127 of wave half (b reused) ----
#pragma unroll
        for (int m = 0; m < 4; ++m)
            a[m] = *(const f16x8*)&At[(wm * 128 + (m + 4) * 16 + lr) * 32 + rq * 8];
        if (tk + 3 < nt) stageB(sb, tk + 3);
        __builtin_amdgcn_s_setprio(1);
#pragma unroll
        for (int m = 0; m < 4; ++m)
#pragma unroll
            for (int n = 0; n < 4; ++n)
                acc[m + 4][n] = __builtin_amdgcn_mfma_f32_16x16x32_f16(a[m], b[n], acc[m + 4][n], 0, 0, 0);
        __builtin_amdgcn_s_setprio(0);
        // ---- tile-end sync: make tile t+1 visible chip-wide ----
        if (tk + 1 < nt) {
            if (tk + 3 < nt)      asm volatile("s_waitcnt vmcnt(8)" ::: "memory");
            else if (tk + 2 < nt) asm volatile("s_waitcnt vmcnt(4)" ::: "memory");
            else                  asm volatile("s_waitcnt vmcnt(0)" ::: "memory");
            __builtin_amdgcn_s_barrier();
        }
    }

    // ---- epilogue: gate + two half-tile LDS bounces -> coalesced stores ----
#pragma unroll
    for (int half = 0; half < 2; ++half) {
        __builtin_amdgcn_s_barrier();
        if (wm == half) {
#pragma unroll
            for (int m = 0; m < 8; ++m)
#pragma unroll
                for (int n = 0; n < 4; ++n)
#pragma unroll
                    for (int j = 0; j < 4; ++j) {
                        const int lrow = m * 16 + lk * 4 + j;
                        const int lcol = wn * 64 + n * 16 + lr;
                        const long row = rowTile + half * 128 + lrow;
                        const float s = (float)G[(row >> 3) * ldc + colTile + lcol];
                        const float g = 1.f - __expf(-s);
                        smem[lrow * 256 + (lcol ^ (lk * 16))] = (f16)(acc[m][n][j] * g);
                    }
        }
        __builtin_amdgcn_s_barrier();
#pragma unroll
        for (int p = 0; p < 8; ++p) {
            const int c = p * 512 + t;
            const int rl = c >> 5;
            const int c16 = (c & 31) * 8;
            const f16x8 v = *(const f16x8*)&smem[rl * 256 + (c16 ^ (((rl >> 2) & 3) * 16))];
            *(f16x8*)&C[(rowTile + half * 128 + rl) * ldc + colTile + c16] = v;
        }
    }
}

// ============================================================================
// Counted-vmcnt GEMM template (R14/R16-proven, distance 2, triple-buffer):
//  fwd      : <EPI_SP,  64,128,256,4>  L=3, 36KB -> 4 blk/CU
//  fwd-out  : <EPI_TANH,128,128,256,2> L=4, 48KB -> 3 blk/CU
//  diag     : <EPI_NONE,128,128,256,2> L=4, z=field -> Oi f16
// ============================================================================
template <int EPI, int BM, int BN, int TPB, int WN>
__global__ __launch_bounds__(TPB, (163840 / (3 * (BM + BN) * 64)) * TPB / 256) void gemmCV(
    const f16* __restrict__ A, int lda, long aZ,
    const f16* __restrict__ W, int ldw, long wZ,
    const float* __restrict__ bias,
    f16* __restrict__ C, int ldc, long cZ,
    const f16* __restrict__ G,
    int K, int cshift)
{
    constexpr int WM = TPB / 64 / WN;
    constexpr int FM = BM / (WM * 16);
    constexpr int FN = BN / (WN * 16);
    constexpr int LA = BM * 4 / TPB;
    constexpr int LB = BN * 4 / TPB;
    constexpr int L  = LA + LB;

    __shared__ __align__(16) f16 smem[3 * (BM + BN) * 32];
    f16* bufA = smem;
    f16* bufB = smem + 3 * BM * 32;

    const int t = threadIdx.x;
    const int z = blockIdx.z;
    A += (size_t)z * aZ;
    W += (size_t)z * wZ;
    C += (size_t)z * cZ;

    const int nxy = gridDim.x * gridDim.y;
    const int orig = blockIdx.x + gridDim.x * blockIdx.y;
    const int q = nxy >> 3, r = nxy & 7;
    const int xcd = orig & 7, idx = orig >> 3;
    const int nid = (xcd < r ? xcd * (q + 1) : r * (q + 1) + (xcd - r) * q) + idx;
    const long rowTile = (long)(nid >> cshift) * BM;
    const long colTile = (long)(nid & ((1 << cshift) - 1)) * BN;

    const int wave = t >> 6;
    const int lane = t & 63;
    const int wr = (wave / WN) * (FM * 16);
    const int wc = (wave % WN) * (FN * 16);
    const int lr = lane & 15;
    const int lk = lane >> 4;
    const int rq = lk ^ (lr & 3);
    const int srow = t >> 2;
    const int skq  = t & 3;

    f32x4 acc[FM][FN];
    const f32x4 zero = {0.f, 0.f, 0.f, 0.f};
#pragma unroll
    for (int m = 0; m < FM; ++m)
#pragma unroll
        for (int n = 0; n < FN; ++n) acc[m][n] = zero;

    const int nt = K >> 5;

    auto stage = [&](int buf, int tk) {
        const int k0 = tk << 5;
#pragma unroll
        for (int p = 0; p < LA; ++p) {
            const int row = srow + p * (TPB / 4);
            gl_lds16(A + (rowTile + row) * (long)lda + k0 + (skq ^ (row & 3)) * 8,
                     &bufA[buf * (BM * 32) + (p * TPB + t) * 8]);
        }
#pragma unroll
        for (int p = 0; p < LB; ++p) {
            const int row = srow + p * (TPB / 4);
            gl_lds16(W + (colTile + row) * (long)ldw + k0 + (skq ^ (row & 3)) * 8,
                     &bufB[buf * (BN * 32) + (p * TPB + t) * 8]);
        }
    };
    auto waitL = [&]() {
        if constexpr (L == 3) asm volatile("s_waitcnt vmcnt(3)" ::: "memory");
        else if constexpr (L == 4) asm volatile("s_waitcnt vmcnt(4)" ::: "memory");
        else asm volatile("s_waitcnt vmcnt(0)" ::: "memory");
    };

    stage(0, 0);
    stage(1, 1);
    waitL();
    __builtin_amdgcn_s_barrier();

    for (int tk = 0; tk < nt; ++tk) {
        const int cb = tk % 3;
        const f16* At = &bufA[cb * (BM * 32)];
        const f16* Bt = &bufB[cb * (BN * 32)];
        f16x8 a[FM], b[FN];
#pragma unroll
        for (int m = 0; m < FM; ++m)
            a[m] = *(const f16x8*)&At[(wr + m * 16 + lr) * 32 + rq * 8];
#pragma unroll
        for (int n = 0; n < FN; ++n)
            b[n] = *(const f16x8*)&Bt[(wc + n * 16 + lr) * 32 + rq * 8];
        if (tk + 2 < nt) stage((tk + 2) % 3, tk + 2);
        __builtin_amdgcn_s_setprio(1);
#pragma unroll
        for (int m = 0; m < FM; ++m)
#pragma unroll
            for (int n = 0; n < FN; ++n)
                acc[m][n] = __builtin_amdgcn_mfma_f32_16x16x32_f16(a[m], b[n], acc[m][n], 0, 0, 0);
        __builtin_amdgcn_s_setprio(0);
        if (tk + 1 < nt) {
            if (tk + 2 < nt) waitL();
            else asm volatile("s_waitcnt vmcnt(0)" ::: "memory");
            __builtin_amdgcn_s_barrier();
        }
    }

    __syncthreads();
#pragma unroll
    for (int m = 0; m < FM; ++m) {
#pragma unroll
        for (int n = 0; n < FN; ++n) {
            const int lcol = wc + n * 16 + lr;
            const float bb = bias ? bias[colTile + lcol] : 0.f;
#pragma unroll
            for (int j = 0; j < 4; ++j) {
                const int lrow = wr + m * 16 + lk * 4 + j;
                const int lidx = lrow * BN + (lcol ^ (lk * 16));
                const float x = acc[m][n][j] + bb;
                if constexpr (EPI == EPI_SP) {
                    const float e = __expf(-fabsf(x));
                    smem[lidx] = (f16)(fmaxf(x, 0.f) + __logf(1.f + e));
                } else if constexpr (EPI == EPI_TANH) {
                    const float e2 = __expf(2.f * x);
                    smem[lidx] = (f16)(1.f - 2.f * __builtin_amdgcn_rcpf(e2 + 1.f));
                } else if constexpr (EPI == EPI_GATE) {
                    const long row = rowTile + lrow;
                    const float s = (float)G[(row >> 3) * ldc + colTile + lcol];
                    smem[lidx] = (f16)(x * (1.f - __expf(-s)));
                } else {
                    smem[lidx] = (f16)x;
                }
            }
        }
    }
    __syncthreads();
#pragma unroll
    for (int p = 0; p < BM * BN / (8 * TPB); ++p) {
        const int c = p * TPB + t;
        const int rl = c / (BN / 8);
        const int c16 = (c % (BN / 8)) * 8;
        const f16x8 v = *(const f16x8*)&smem[rl * BN + (c16 ^ (((rl >> 2) & 3) * 16))];
        *(f16x8*)&C[(rowTile + rl) * ldc + colTile + c16] = v;
    }
}

// T[b,i,n] = sum_{k<i} sig2[(k,i)] V[b,k,n] - sum_{k>i} sig2[(i,k)] V[b,k,n]
__global__ __launch_bounds__(256) void ktilde16(
    const f16* __restrict__ V, const float* __restrict__ sig,
    f16* __restrict__ T, int b0)
{
    const int bl = blockIdx.x * 4 + (threadIdx.x >> 6);
    const int n0 = (threadIdx.x & 63) * 4;
    const f16* vb = V + (size_t)bl * 2048 + n0;
    float v[8][4];
#pragma unroll
    for (int k = 0; k < 8; ++k) {
        const f16x4 x = *(const f16x4*)&vb[k * 256];
#pragma unroll
        for (int j = 0; j < 4; ++j) v[k][j] = (float)x[j];
    }
    const float* sg = sig + (size_t)(b0 + bl) * MM + 8;
    float s2[28];
#pragma unroll
    for (int p = 0; p < 28; ++p) s2[p] = sg[p];

    f16* tb = T + (size_t)bl * 2048 + n0;
#pragma unroll
    for (int i = 0; i < 8; ++i) {
        float a0 = 0.f, a1 = 0.f, a2 = 0.f, a3 = 0.f;
#pragma unroll
        for (int k = 0; k < 8; ++k) {
            if (k == i) continue;
            const int a = (k < i) ? k : i;
            const int b = (k < i) ? i : k;
            const int p = a * (15 - a) / 2 + (b - a - 1);
            const float c = (k < i) ? s2[p] : -s2[p];
            a0 = fmaf(c, v[k][0], a0); a1 = fmaf(c, v[k][1], a1);
            a2 = fmaf(c, v[k][2], a2); a3 = fmaf(c, v[k][3], a3);
        }
        f16x4 o;
        o[0] = (f16)a0; o[1] = (f16)a1; o[2] = (f16)a2; o[3] = (f16)a3;
        *(f16x4*)&tb[i * 256] = o;
    }
}

// out[b,n] = sum_i sig[b,i]*V[b,i,n] + (1 - V^2) * Oi[i][b][n]   (Oi is f16)
__global__ __launch_bounds__(256) void finish16(
    const f16* __restrict__ V, const f16* __restrict__ Oi,
    const float* __restrict__ sig, float* __restrict__ out, int b0, int C)
{
    const int bl = blockIdx.x * 4 + (threadIdx.x >> 6);
    const int n0 = (threadIdx.x & 63) * 4;
    const float* sg = sig + (size_t)(b0 + bl) * MM;
    float a0 = 0.f, a1 = 0.f, a2 = 0.f, a3 = 0.f;
#pragma unroll
    for (int i = 0; i < 8; ++i) {
        const f16x4 vv = *(const f16x4*)&V[(size_t)bl * 2048 + i * 256 + n0];
        const f16x4 oo = *(const f16x4*)&Oi[((size_t)i * C + bl) * 256 + n0];
        const float s = sg[i];
        const float v0 = (float)vv[0], v1 = (float)vv[1];
        const float v2 = (float)vv[2], v3 = (float)vv[3];
        a0 = fmaf(s, v0, a0); a0 = fmaf(1.f - v0 * v0, (float)oo[0], a0);
        a1 = fmaf(s, v1, a1); a1 = fmaf(1.f - v1 * v1, (float)oo[1], a1);
        a2 = fmaf(s, v2, a2); a2 = fmaf(1.f - v2 * v2, (float)oo[2], a2);
        a3 = fmaf(s, v3, a3); a3 = fmaf(1.f - v3 * v3, (float)oo[3], a3);
    }
    float4 ov; ov.x = a0; ov.y = a1; ov.z = a2; ov.w = a3;
    *(float4*)&out[(size_t)(b0 + bl) * 256 + n0] = ov;
}

// one-shot f32->f16 of all four weight matrices (float4 granularity)
__global__ __launch_bounds__(256) void cvtW(
    const float* __restrict__ W1, const float* __restrict__ W2,
    const float* __restrict__ W3, const float* __restrict__ Wo,
    f16* __restrict__ o1, f16* __restrict__ o2,
    f16* __restrict__ o3, f16* __restrict__ oo)
{
    long i = (long)blockIdx.x * 256 + threadIdx.x;
    const float* src; f16* dst; long base;
    if (i < 32768)       { src = W1; dst = o1; base = 0; }
    else if (i < 98304)  { src = W2; dst = o2; base = 32768; }
    else if (i < 163840) { src = W3; dst = o3; base = 98304; }
    else                 { src = Wo; dst = oo; base = 163840; }
    i -= base;
    const float4 v = ((const float4*)src)[i];
    f16x4 o;
    o[0] = (f16)v.x; o[1] = (f16)v.y; o[2] = (f16)v.z; o[3] = (f16)v.w;
    ((f16x4*)dst)[i] = o;
}

__global__ __launch_bounds__(256) void cvt16(
    const float* __restrict__ x, f16* __restrict__ y, int n)
{
    const int i = (blockIdx.x * 256 + threadIdx.x) * 4;
    if (i < n) {
        const float4 v = *(const float4*)&x[i];
        f16x4 o;
        o[0] = (f16)v.x; o[1] = (f16)v.y; o[2] = (f16)v.z; o[3] = (f16)v.w;
        *(f16x4*)&y[i] = o;
    }
}

extern "C" void kernel_launch(void* const* d_in, const int* in_sizes, int n_in,
                              void* d_out, int out_size, void* d_ws, size_t ws_size,
                              hipStream_t stream) {
    const float* h   = (const float*)d_in[0];
    const float* sig = (const float*)d_in[1];
    const float* W1  = (const float*)d_in[2];
    const float* b1  = (const float*)d_in[3];
    const float* W2  = (const float*)d_in[4];
    const float* b2  = (const float*)d_in[5];
    const float* W3  = (const float*)d_in[6];
    const float* b3  = (const float*)d_in[7];
    const float* Wo  = (const float*)d_in[8];
    const float* bo  = (const float*)d_in[9];
    float* out = (float*)d_out;

    char* p = (char*)d_ws;
    f16* W1h = (f16*)p; p += (size_t)512 * 256 * 2;
    f16* W2h = (f16*)p; p += (size_t)512 * 512 * 2;
    f16* W3h = (f16*)p; p += (size_t)512 * 512 * 2;
    f16* Woh = (f16*)p; p += (size_t)2048 * 512 * 2;
    const size_t fixed = (size_t)(p - (char*)d_ws);

    int C = 4096;
    while (C > 128 && fixed + (size_t)C * 28160 > ws_size) C >>= 1;

    f16* h16 = (f16*)p; p += (size_t)C * 256 * 2;
    f16* s1 = (f16*)p;  p += (size_t)C * 512 * 2;
    f16* s2 = (f16*)p;  p += (size_t)C * 512 * 2;
    f16* s3 = (f16*)p;  p += (size_t)C * 512 * 2;
    f16* V  = (f16*)p;  p += (size_t)C * 2048 * 2;
    f16* T  = (f16*)p;  p += (size_t)C * 2048 * 2;
    f16* Ua = (f16*)p;  p += (size_t)C * 4096 * 2;
    f16* Ub = (f16*)p;
    f16* Oi = Ub;                         // 8 x C x 256 f16 (Ub dead before diag)

    const dim3 blk(256);
    const dim3 blk5(512);
    cvtW<<<dim3(1664), blk, 0, stream>>>(W1, W2, W3, Wo, W1h, W2h, W3h, Woh);

    for (int b0 = 0; b0 < 4096; b0 += C) {
        cvt16<<<dim3(C * 256 / 1024), blk, 0, stream>>>(h + (size_t)b0 * 256, h16, C * 256);
        // Forward MLP (counted-vmcnt template)
        gemmCV<EPI_SP, 64, 128, 256, 4><<<dim3(4, C / 64), blk, 0, stream>>>(
            h16, 256, 0, W1h, 256, 0, b1, s1, 512, 0, nullptr, 256, 2);
        gemmCV<EPI_SP, 64, 128, 256, 4><<<dim3(4, C / 64), blk, 0, stream>>>(
            s1, 512, 0, W2h, 512, 0, b2, s2, 512, 0, nullptr, 512, 2);
        gemmCV<EPI_SP, 64, 128, 256, 4><<<dim3(4, C / 64), blk, 0, stream>>>(
            s2, 512, 0, W3h, 512, 0, b3, s3, 512, 0, nullptr, 512, 2);
        gemmCV<EPI_TANH, 128, 128, 256, 2><<<dim3(16, C / 128), blk, 0, stream>>>(
            s3, 512, 0, Woh, 512, 0, bo, V, 2048, 0, nullptr, 512, 4);
        // Signature-mixed tangents
        ktilde16<<<dim3(C / 4), blk, 0, stream>>>(V, sig, T, b0);
        // JVP chain: 256x256 gemm8p, distance-3 quad-buffer
        gemm8p<<<dim3(2, C * 8 / 256), blk5, 0, stream>>>(
            T, 256, W1h, 256, Ua, 512, s1, 256);
        gemm8p<<<dim3(2, C * 8 / 256), blk5, 0, stream>>>(
            Ua, 512, W2h, 512, Ub, 512, s2, 512);
        gemm8p<<<dim3(2, C * 8 / 256), blk5, 0, stream>>>(
            Ub, 512, W3h, 512, Ua, 512, s3, 512);
        // Per-field diagonal last-layer JVP (z = field), Oi stored f16
        gemmCV<EPI_NONE, 128, 128, 256, 2><<<dim3(2, C / 128, 8), blk, 0, stream>>>(
            Ua, 4096, 512, Woh, 512, (long)256 * 512, nullptr, Oi, 256, (long)C * 256,
            nullptr, 512, 1);
        // Final contraction
        finish16<<<dim3(C / 4), blk, 0, stream>>>(V, Oi, sig, out, b0, C);
    }
}

// Round 22
// 156.361 us; speedup vs baseline: 2.4683x; 1.0253x over previous
//
#include <hip/hip_runtime.h>
#include <hip/hip_bf16.h>
#include <math.h>

#define MM 36

typedef _Float16 f16;
typedef __attribute__((ext_vector_type(8))) _Float16 f16x8;
typedef __attribute__((ext_vector_type(4))) _Float16 f16x4;
typedef __attribute__((ext_vector_type(4))) float f32x4;

enum { EPI_NONE = 0, EPI_SP = 1, EPI_TANH = 2, EPI_GATE = 3 };

// async global->LDS, 16B per lane. LDS dest must be wave-uniform base + lane*16.
__device__ __forceinline__ void gl_lds16(const f16* g, f16* l) {
    __builtin_amdgcn_global_load_lds(
        (const __attribute__((address_space(1))) void*)g,
        (__attribute__((address_space(3))) void*)l, 16, 0, 0);
}

// ============================================================================
// JVP counted-vmcnt GEMM (R14/R20-proven; quad-buffer distance-3):
// C = gate * A W^T, 256x256 tile, BK=32, 512 thr, 128KB LDS, 1 blk/CU.
// 2-blk/CU variant refuted by VGPR arithmetic (acc=128 VGPR > 128/wave cap
// at 4 waves/SIMD). Unchanged from R20.
// ============================================================================
__global__ __launch_bounds__(512, 1) void gemm8p(
    const f16* __restrict__ A, int lda,
    const f16* __restrict__ W, int ldw,
    f16* __restrict__ C, int ldc,
    const f16* __restrict__ G,
    int K)
{
    __shared__ __align__(16) f16 smem[65536];   // 4 x (8192 A + 8192 B) = 128 KB
    f16* bufA = smem;
    f16* bufB = smem + 32768;

    const int t = threadIdx.x;
    const int nxy = gridDim.x * gridDim.y;      // divisible by 8
    const int orig = blockIdx.x + gridDim.x * blockIdx.y;
    const int q = nxy >> 3, r = nxy & 7;
    const int xcd = orig & 7, idx = orig >> 3;
    const int nid = (xcd < r ? xcd * (q + 1) : r * (q + 1) + (xcd - r) * q) + idx;
    const long rowTile = (long)(nid >> 1) * 256;
    const long colTile = (long)(nid & 1) * 256;

    const int wave = t >> 6;
    const int lane = t & 63;
    const int wm = wave >> 2;           // 0..1 (row half)
    const int wn = wave & 3;            // 0..3 (col quarter)
    const int lr = lane & 15;
    const int lk = lane >> 4;           // k-group
    const int rq = lk ^ (lr & 3);       // swizzled k-quad for frag reads

    const int srow = t >> 2;            // staging row (pass p adds 128)
    const int skq  = t & 3;             // staging k-quad (pre-swizzled source)

    f32x4 acc[8][4];
    const f32x4 zero = {0.f, 0.f, 0.f, 0.f};
#pragma unroll
    for (int m = 0; m < 8; ++m)
#pragma unroll
        for (int n = 0; n < 4; ++n) acc[m][n] = zero;

    const int nt = K >> 5;

    auto stageA = [&](int buf, int tk) {
        const int k0 = tk << 5;
#pragma unroll
        for (int p = 0; p < 2; ++p) {
            const int row = srow + p * 128;
            gl_lds16(A + (rowTile + row) * (long)lda + k0 + (skq ^ (row & 3)) * 8,
                     &bufA[buf * 8192 + (p * 512 + t) * 8]);
        }
    };
    auto stageB = [&](int buf, int tk) {
        const int k0 = tk << 5;
#pragma unroll
        for (int p = 0; p < 2; ++p) {
            const int row = srow + p * 128;
            gl_lds16(W + (colTile + row) * (long)ldw + k0 + (skq ^ (row & 3)) * 8,
                     &bufB[buf * 8192 + (p * 512 + t) * 8]);
        }
    };

    // prologue: stage K-tiles 0,1,2; await tile 0 (8 newer loads allowed)
    stageA(0, 0); stageB(0, 0);
    stageA(1, 1); stageB(1, 1);
    stageA(2, 2); stageB(2, 2);
    asm volatile("s_waitcnt vmcnt(8)" ::: "memory");   // own tile-0 loads landed
    __builtin_amdgcn_s_barrier();                       // => ALL waves' landed

    for (int tk = 0; tk < nt; ++tk) {
        const int cb = tk & 3;
        const int sb = (tk + 3) & 3;
        const f16* At = &bufA[cb * 8192];
        const f16* Bt = &bufB[cb * 8192];
        f16x8 a[4], b[4];
        // ---- phase 0: rows 0-63 of wave half ----
#pragma unroll
        for (int m = 0; m < 4; ++m)
            a[m] = *(const f16x8*)&At[(wm * 128 + m * 16 + lr) * 32 + rq * 8];
#pragma unroll
        for (int n = 0; n < 4; ++n)
            b[n] = *(const f16x8*)&Bt[(wn * 64 + n * 16 + lr) * 32 + rq * 8];
        if (tk + 3 < nt) stageA(sb, tk + 3);
        __builtin_amdgcn_s_setprio(1);
#pragma unroll
        for (int m = 0; m < 4; ++m)
#pragma unroll
            for (int n = 0; n < 4; ++n)
                acc[m][n] = __builtin_amdgcn_mfma_f32_16x16x32_f16(a[m], b[n], acc[m][n], 0, 0, 0);
        __builtin_amdgcn_s_setprio(0);
        // ---- phase 1: rows 64-127 of wave half (b reused) ----
#pragma unroll
        for (int m = 0; m < 4; ++m)
            a[m] = *(const f16x8*)&At[(wm * 128 + (m + 4) * 16 + lr) * 32 + rq * 8];
        if (tk + 3 < nt) stageB(sb, tk + 3);
        __builtin_amdgcn_s_setprio(1);
#pragma unroll
        for (int m = 0; m < 4; ++m)
#pragma unroll
            for (int n = 0; n < 4; ++n)
                acc[m + 4][n] = __builtin_amdgcn_mfma_f32_16x16x32_f16(a[m], b[n], acc[m + 4][n], 0, 0, 0);
        __builtin_amdgcn_s_setprio(0);
        // ---- tile-end sync: make tile t+1 visible chip-wide ----
        if (tk + 1 < nt) {
            if (tk + 3 < nt)      asm volatile("s_waitcnt vmcnt(8)" ::: "memory");
            else if (tk + 2 < nt) asm volatile("s_waitcnt vmcnt(4)" ::: "memory");
            else                  asm volatile("s_waitcnt vmcnt(0)" ::: "memory");
            __builtin_amdgcn_s_barrier();
        }
    }

    // ---- epilogue: gate + two half-tile LDS bounces -> coalesced stores ----
#pragma unroll
    for (int half = 0; half < 2; ++half) {
        __builtin_amdgcn_s_barrier();
        if (wm == half) {
#pragma unroll
            for (int m = 0; m < 8; ++m)
#pragma unroll
                for (int n = 0; n < 4; ++n)
#pragma unroll
                    for (int j = 0; j < 4; ++j) {
                        const int lrow = m * 16 + lk * 4 + j;
                        const int lcol = wn * 64 + n * 16 + lr;
                        const long row = rowTile + half * 128 + lrow;
                        const float s = (float)G[(row >> 3) * ldc + colTile + lcol];
                        const float g = 1.f - __expf(-s);
                        smem[lrow * 256 + (lcol ^ (lk * 16))] = (f16)(acc[m][n][j] * g);
                    }
        }
        __builtin_amdgcn_s_barrier();
#pragma unroll
        for (int p = 0; p < 8; ++p) {
            const int c = p * 512 + t;
            const int rl = c >> 5;
            const int c16 = (c & 31) * 8;
            const f16x8 v = *(const f16x8*)&smem[rl * 256 + (c16 ^ (((rl >> 2) & 3) * 16))];
            *(f16x8*)&C[(rowTile + half * 128 + rl) * ldc + colTile + c16] = v;
        }
    }
}

// ============================================================================
// Counted-vmcnt GEMM template (R14/R16-proven, distance 2, triple-buffer):
//  fwd      : <EPI_SP,  64, 64,256,2>  L=2, 24KB -> 512 blocks, 2 blk/CU
//             (BN=128 gave 256 blocks = 1 wave/SIMD = zero stall hiding)
//  fwd-out  : <EPI_TANH,128,128,256,2> L=4, 48KB -> 3 blk/CU
//  diag     : <EPI_NONE,128,128,256,2> L=4, z=field -> Oi f16
// ============================================================================
template <int EPI, int BM, int BN, int TPB, int WN>
__global__ __launch_bounds__(TPB, (163840 / (3 * (BM + BN) * 64)) * TPB / 256) void gemmCV(
    const f16* __restrict__ A, int lda, long aZ,
    const f16* __restrict__ W, int ldw, long wZ,
    const float* __restrict__ bias,
    f16* __restrict__ C, int ldc, long cZ,
    const f16* __restrict__ G,
    int K, int cshift)
{
    constexpr int WM = TPB / 64 / WN;
    constexpr int FM = BM / (WM * 16);
    constexpr int FN = BN / (WN * 16);
    constexpr int LA = BM * 4 / TPB;
    constexpr int LB = BN * 4 / TPB;
    constexpr int L  = LA + LB;

    __shared__ __align__(16) f16 smem[3 * (BM + BN) * 32];
    f16* bufA = smem;
    f16* bufB = smem + 3 * BM * 32;

    const int t = threadIdx.x;
    const int z = blockIdx.z;
    A += (size_t)z * aZ;
    W += (size_t)z * wZ;
    C += (size_t)z * cZ;

    const int nxy = gridDim.x * gridDim.y;
    const int orig = blockIdx.x + gridDim.x * blockIdx.y;
    const int q = nxy >> 3, r = nxy & 7;
    const int xcd = orig & 7, idx = orig >> 3;
    const int nid = (xcd < r ? xcd * (q + 1) : r * (q + 1) + (xcd - r) * q) + idx;
    const long rowTile = (long)(nid >> cshift) * BM;
    const long colTile = (long)(nid & ((1 << cshift) - 1)) * BN;

    const int wave = t >> 6;
    const int lane = t & 63;
    const int wr = (wave / WN) * (FM * 16);
    const int wc = (wave % WN) * (FN * 16);
    const int lr = lane & 15;
    const int lk = lane >> 4;
    const int rq = lk ^ (lr & 3);
    const int srow = t >> 2;
    const int skq  = t & 3;

    f32x4 acc[FM][FN];
    const f32x4 zero = {0.f, 0.f, 0.f, 0.f};
#pragma unroll
    for (int m = 0; m < FM; ++m)
#pragma unroll
        for (int n = 0; n < FN; ++n) acc[m][n] = zero;

    const int nt = K >> 5;

    auto stage = [&](int buf, int tk) {
        const int k0 = tk << 5;
#pragma unroll
        for (int p = 0; p < LA; ++p) {
            const int row = srow + p * (TPB / 4);
            gl_lds16(A + (rowTile + row) * (long)lda + k0 + (skq ^ (row & 3)) * 8,
                     &bufA[buf * (BM * 32) + (p * TPB + t) * 8]);
        }
#pragma unroll
        for (int p = 0; p < LB; ++p) {
            const int row = srow + p * (TPB / 4);
            gl_lds16(W + (colTile + row) * (long)ldw + k0 + (skq ^ (row & 3)) * 8,
                     &bufB[buf * (BN * 32) + (p * TPB + t) * 8]);
        }
    };
    auto waitL = [&]() {
        if constexpr (L == 2) asm volatile("s_waitcnt vmcnt(2)" ::: "memory");
        else if constexpr (L == 3) asm volatile("s_waitcnt vmcnt(3)" ::: "memory");
        else if constexpr (L == 4) asm volatile("s_waitcnt vmcnt(4)" ::: "memory");
        else asm volatile("s_waitcnt vmcnt(0)" ::: "memory");
    };

    stage(0, 0);
    stage(1, 1);
    waitL();
    __builtin_amdgcn_s_barrier();

    for (int tk = 0; tk < nt; ++tk) {
        const int cb = tk % 3;
        const f16* At = &bufA[cb * (BM * 32)];
        const f16* Bt = &bufB[cb * (BN * 32)];
        f16x8 a[FM], b[FN];
#pragma unroll
        for (int m = 0; m < FM; ++m)
            a[m] = *(const f16x8*)&At[(wr + m * 16 + lr) * 32 + rq * 8];
#pragma unroll
        for (int n = 0; n < FN; ++n)
            b[n] = *(const f16x8*)&Bt[(wc + n * 16 + lr) * 32 + rq * 8];
        if (tk + 2 < nt) stage((tk + 2) % 3, tk + 2);
        __builtin_amdgcn_s_setprio(1);
#pragma unroll
        for (int m = 0; m < FM; ++m)
#pragma unroll
            for (int n = 0; n < FN; ++n)
                acc[m][n] = __builtin_amdgcn_mfma_f32_16x16x32_f16(a[m], b[n], acc[m][n], 0, 0, 0);
        __builtin_amdgcn_s_setprio(0);
        if (tk + 1 < nt) {
            if (tk + 2 < nt) waitL();
            else asm volatile("s_waitcnt vmcnt(0)" ::: "memory");
            __builtin_amdgcn_s_barrier();
        }
    }

    __syncthreads();
#pragma unroll
    for (int m = 0; m < FM; ++m) {
#pragma unroll
        for (int n = 0; n < FN; ++n) {
            const int lcol = wc + n * 16 + lr;
            const float bb = bias ? bias[colTile + lcol] : 0.f;
#pragma unroll
            for (int j = 0; j < 4; ++j) {
                const int lrow = wr + m * 16 + lk * 4 + j;
                const int lidx = lrow * BN + (lcol ^ (lk * 16));
                const float x = acc[m][n][j] + bb;
                if constexpr (EPI == EPI_SP) {
                    const float e = __expf(-fabsf(x));
                    smem[lidx] = (f16)(fmaxf(x, 0.f) + __logf(1.f + e));
                } else if constexpr (EPI == EPI_TANH) {
                    const float e2 = __expf(2.f * x);
                    smem[lidx] = (f16)(1.f - 2.f * __builtin_amdgcn_rcpf(e2 + 1.f));
                } else if constexpr (EPI == EPI_GATE) {
                    const long row = rowTile + lrow;
                    const float s = (float)G[(row >> 3) * ldc + colTile + lcol];
                    smem[lidx] = (f16)(x * (1.f - __expf(-s)));
                } else {
                    smem[lidx] = (f16)x;
                }
            }
        }
    }
    __syncthreads();
#pragma unroll
    for (int p = 0; p < BM * BN / (8 * TPB); ++p) {
        const int c = p * TPB + t;
        const int rl = c / (BN / 8);
        const int c16 = (c % (BN / 8)) * 8;
        const f16x8 v = *(const f16x8*)&smem[rl * BN + (c16 ^ (((rl >> 2) & 3) * 16))];
        *(f16x8*)&C[(rowTile + rl) * ldc + colTile + c16] = v;
    }
}

// T[b,i,n] = sum_{k<i} sig2[(k,i)] V[b,k,n] - sum_{k>i} sig2[(i,k)] V[b,k,n]
__global__ __launch_bounds__(256) void ktilde16(
    const f16* __restrict__ V, const float* __restrict__ sig,
    f16* __restrict__ T, int b0)
{
    const int bl = blockIdx.x * 4 + (threadIdx.x >> 6);
    const int n0 = (threadIdx.x & 63) * 4;
    const f16* vb = V + (size_t)bl * 2048 + n0;
    float v[8][4];
#pragma unroll
    for (int k = 0; k < 8; ++k) {
        const f16x4 x = *(const f16x4*)&vb[k * 256];
#pragma unroll
        for (int j = 0; j < 4; ++j) v[k][j] = (float)x[j];
    }
    const float* sg = sig + (size_t)(b0 + bl) * MM + 8;
    float s2[28];
#pragma unroll
    for (int p = 0; p < 28; ++p) s2[p] = sg[p];

    f16* tb = T + (size_t)bl * 2048 + n0;
#pragma unroll
    for (int i = 0; i < 8; ++i) {
        float a0 = 0.f, a1 = 0.f, a2 = 0.f, a3 = 0.f;
#pragma unroll
        for (int k = 0; k < 8; ++k) {
            if (k == i) continue;
            const int a = (k < i) ? k : i;
            const int b = (k < i) ? i : k;
            const int p = a * (15 - a) / 2 + (b - a - 1);
            const float c = (k < i) ? s2[p] : -s2[p];
            a0 = fmaf(c, v[k][0], a0); a1 = fmaf(c, v[k][1], a1);
            a2 = fmaf(c, v[k][2], a2); a3 = fmaf(c, v[k][3], a3);
        }
        f16x4 o;
        o[0] = (f16)a0; o[1] = (f16)a1; o[2] = (f16)a2; o[3] = (f16)a3;
        *(f16x4*)&tb[i * 256] = o;
    }
}

// out[b,n] = sum_i sig[b,i]*V[b,i,n] + (1 - V^2) * Oi[i][b][n]   (Oi is f16)
__global__ __launch_bounds__(256) void finish16(
    const f16* __restrict__ V, const f16* __restrict__ Oi,
    const float* __restrict__ sig, float* __restrict__ out, int b0, int C)
{
    const int bl = blockIdx.x * 4 + (threadIdx.x >> 6);
    const int n0 = (threadIdx.x & 63) * 4;
    const float* sg = sig + (size_t)(b0 + bl) * MM;
    float a0 = 0.f, a1 = 0.f, a2 = 0.f, a3 = 0.f;
#pragma unroll
    for (int i = 0; i < 8; ++i) {
        const f16x4 vv = *(const f16x4*)&V[(size_t)bl * 2048 + i * 256 + n0];
        const f16x4 oo = *(const f16x4*)&Oi[((size_t)i * C + bl) * 256 + n0];
        const float s = sg[i];
        const float v0 = (float)vv[0], v1 = (float)vv[1];
        const float v2 = (float)vv[2], v3 = (float)vv[3];
        a0 = fmaf(s, v0, a0); a0 = fmaf(1.f - v0 * v0, (float)oo[0], a0);
        a1 = fmaf(s, v1, a1); a1 = fmaf(1.f - v1 * v1, (float)oo[1], a1);
        a2 = fmaf(s, v2, a2); a2 = fmaf(1.f - v2 * v2, (float)oo[2], a2);
        a3 = fmaf(s, v3, a3); a3 = fmaf(1.f - v3 * v3, (float)oo[3], a3);
    }
    float4 ov; ov.x = a0; ov.y = a1; ov.z = a2; ov.w = a3;
    *(float4*)&out[(size_t)(b0 + bl) * 256 + n0] = ov;
}

// one-shot f32->f16 of all four weight matrices (float4 granularity)
__global__ __launch_bounds__(256) void cvtW(
    const float* __restrict__ W1, const float* __restrict__ W2,
    const float* __restrict__ W3, const float* __restrict__ Wo,
    f16* __restrict__ o1, f16* __restrict__ o2,
    f16* __restrict__ o3, f16* __restrict__ oo)
{
    long i = (long)blockIdx.x * 256 + threadIdx.x;
    const float* src; f16* dst; long base;
    if (i < 32768)       { src = W1; dst = o1; base = 0; }
    else if (i < 98304)  { src = W2; dst = o2; base = 32768; }
    else if (i < 163840) { src = W3; dst = o3; base = 98304; }
    else                 { src = Wo; dst = oo; base = 163840; }
    i -= base;
    const float4 v = ((const float4*)src)[i];
    f16x4 o;
    o[0] = (f16)v.x; o[1] = (f16)v.y; o[2] = (f16)v.z; o[3] = (f16)v.w;
    ((f16x4*)dst)[i] = o;
}

__global__ __launch_bounds__(256) void cvt16(
    const float* __restrict__ x, f16* __restrict__ y, int n)
{
    const int i = (blockIdx.x * 256 + threadIdx.x) * 4;
    if (i < n) {
        const float4 v = *(const float4*)&x[i];
        f16x4 o;
        o[0] = (f16)v.x; o[1] = (f16)v.y; o[2] = (f16)v.z; o[3] = (f16)v.w;
        *(f16x4*)&y[i] = o;
    }
}

extern "C" void kernel_launch(void* const* d_in, const int* in_sizes, int n_in,
                              void* d_out, int out_size, void* d_ws, size_t ws_size,
                              hipStream_t stream) {
    const float* h   = (const float*)d_in[0];
    const float* sig = (const float*)d_in[1];
    const float* W1  = (const float*)d_in[2];
    const float* b1  = (const float*)d_in[3];
    const float* W2  = (const float*)d_in[4];
    const float* b2  = (const float*)d_in[5];
    const float* W3  = (const float*)d_in[6];
    const float* b3  = (const float*)d_in[7];
    const float* Wo  = (const float*)d_in[8];
    const float* bo  = (const float*)d_in[9];
    float* out = (float*)d_out;

    char* p = (char*)d_ws;
    f16* W1h = (f16*)p; p += (size_t)512 * 256 * 2;
    f16* W2h = (f16*)p; p += (size_t)512 * 512 * 2;
    f16* W3h = (f16*)p; p += (size_t)512 * 512 * 2;
    f16* Woh = (f16*)p; p += (size_t)2048 * 512 * 2;
    const size_t fixed = (size_t)(p - (char*)d_ws);

    int C = 4096;
    while (C > 128 && fixed + (size_t)C * 28160 > ws_size) C >>= 1;

    f16* h16 = (f16*)p; p += (size_t)C * 256 * 2;
    f16* s1 = (f16*)p;  p += (size_t)C * 512 * 2;
    f16* s2 = (f16*)p;  p += (size_t)C * 512 * 2;
    f16* s3 = (f16*)p;  p += (size_t)C * 512 * 2;
    f16* V  = (f16*)p;  p += (size_t)C * 2048 * 2;
    f16* T  = (f16*)p;  p += (size_t)C * 2048 * 2;
    f16* Ua = (f16*)p;  p += (size_t)C * 4096 * 2;
    f16* Ub = (f16*)p;
    f16* Oi = Ub;                         // 8 x C x 256 f16 (Ub dead before diag)

    const dim3 blk(256);
    const dim3 blk5(512);
    cvtW<<<dim3(1664), blk, 0, stream>>>(W1, W2, W3, Wo, W1h, W2h, W3h, Woh);

    for (int b0 = 0; b0 < 4096; b0 += C) {
        cvt16<<<dim3(C * 256 / 1024), blk, 0, stream>>>(h + (size_t)b0 * 256, h16, C * 256);
        // Forward MLP (BN=64 -> 512 blocks, 2 blk/CU for stall hiding)
        gemmCV<EPI_SP, 64, 64, 256, 2><<<dim3(8, C / 64), blk, 0, stream>>>(
            h16, 256, 0, W1h, 256, 0, b1, s1, 512, 0, nullptr, 256, 3);
        gemmCV<EPI_SP, 64, 64, 256, 2><<<dim3(8, C / 64), blk, 0, stream>>>(
            s1, 512, 0, W2h, 512, 0, b2, s2, 512, 0, nullptr, 512, 3);
        gemmCV<EPI_SP, 64, 64, 256, 2><<<dim3(8, C / 64), blk, 0, stream>>>(
            s2, 512, 0, W3h, 512, 0, b3, s3, 512, 0, nullptr, 512, 3);
        gemmCV<EPI_TANH, 128, 128, 256, 2><<<dim3(16, C / 128), blk, 0, stream>>>(
            s3, 512, 0, Woh, 512, 0, bo, V, 2048, 0, nullptr, 512, 4);
        // Signature-mixed tangents
        ktilde16<<<dim3(C / 4), blk, 0, stream>>>(V, sig, T, b0);
        // JVP chain: 256x256 gemm8p (proven; prefetch depth is not the binder)
        gemm8p<<<dim3(2, C * 8 / 256), blk5, 0, stream>>>(
            T, 256, W1h, 256, Ua, 512, s1, 256);
        gemm8p<<<dim3(2, C * 8 / 256), blk5, 0, stream>>>(
            Ua, 512, W2h, 512, Ub, 512, s2, 512);
        gemm8p<<<dim3(2, C * 8 / 256), blk5, 0, stream>>>(
            Ub, 512, W3h, 512, Ua, 512, s3, 512);
        // Per-field diagonal last-layer JVP (z = field), Oi stored f16
        gemmCV<EPI_NONE, 128, 128, 256, 2><<<dim3(2, C / 128, 8), blk, 0, stream>>>(
            Ua, 4096, 512, Woh, 512, (long)256 * 512, nullptr, Oi, 256, (long)C * 256,
            nullptr, 512, 1);
        // Final contraction
        finish16<<<dim3(C / 4), blk, 0, stream>>>(V, Oi, sig, out, b0, C);
    }
}